// Round 15
// baseline (223.952 us; speedup 1.0000x reference)
//
#include <hip/hip_runtime.h>

#define NROWS 8192
#define DDIM 512
#define ZROWS 16384
#define BM 128
#define BN 128
#define BK 64
#define KTILES (DDIM / BK)     // 8
#define NLR_BLOCKS 4096        // 64 x 64 (tm x lr-col-panel)
#define NSYM_BLOCKS 2080       // upper triangle incl diag of 64
#define NBLOCKS (NLR_BLOCKS + NSYM_BLOCKS)   // 6176
#define NPANELS 128            // 16384 / 128 col panels

typedef __attribute__((ext_vector_type(8))) short short8;
typedef __attribute__((ext_vector_type(4))) float f32x4;

__device__ __forceinline__ unsigned short f2bf(float f) {
  unsigned int u = __float_as_uint(f);
  u = (u + 0x7FFFu + ((u >> 16) & 1u)) >> 16;
  return (unsigned short)u;
}

// Kernel 1: per-row L2 normalize both inputs, write bf16 Z = [zl; zr],
// and compute the fp32 diagonal cosine sim dlr[i] = zl_i . zr_i.
__global__ __launch_bounds__(256) void nrm_kernel(const float* __restrict__ left,
                                                  const float* __restrict__ right,
                                                  unsigned short* __restrict__ Z,
                                                  float* __restrict__ dlr) {
  const int i = blockIdx.x;
  const int t = threadIdx.x;
  const float2 lv = ((const float2*)(left + (size_t)i * DDIM))[t];
  const float2 rv = ((const float2*)(right + (size_t)i * DDIM))[t];
  float ssl = lv.x * lv.x + lv.y * lv.y;
  float ssr = rv.x * rv.x + rv.y * rv.y;
  float slr = lv.x * rv.x + lv.y * rv.y;
#pragma unroll
  for (int m = 1; m < 64; m <<= 1) {
    ssl += __shfl_xor(ssl, m);
    ssr += __shfl_xor(ssr, m);
    slr += __shfl_xor(slr, m);
  }
  __shared__ float red[3][4];
  const int w = t >> 6;
  if ((t & 63) == 0) { red[0][w] = ssl; red[1][w] = ssr; red[2][w] = slr; }
  __syncthreads();
  ssl = red[0][0] + red[0][1] + red[0][2] + red[0][3];
  ssr = red[1][0] + red[1][1] + red[1][2] + red[1][3];
  slr = red[2][0] + red[2][1] + red[2][2] + red[2][3];
  const float invl = 1.0f / fmaxf(sqrtf(ssl), 1e-12f);
  const float invr = 1.0f / fmaxf(sqrtf(ssr), 1e-12f);
  if (t == 0) dlr[i] = slr * invl * invr;
  ushort2 zl2; zl2.x = f2bf(lv.x * invl); zl2.y = f2bf(lv.y * invl);
  ushort2 zr2; zr2.x = f2bf(rv.x * invr); zr2.y = f2bf(rv.y * invr);
  ((ushort2*)(Z + (size_t)i * DDIM))[t] = zl2;
  ((ushort2*)(Z + (size_t)(NROWS + i) * DDIM))[t] = zr2;
}

// Kernel 2: fused GEMM + exp-rowsum with ll-symmetry at 128^2 granularity.
// R14 structure (4 blocks/CU co-residency via __launch_bounds__(256,4),
// single-buffered 32 KiB LDS, per-kt drain covered by co-resident blocks)
// + R15 change: FULL kt unroll + hoisted addressing. All LDS read addresses
// are kt-invariant and all staging addresses advance by compile-time
// constants, so the unrolled loop folds them into SGPR adds / offset:N
// immediates — removing the ~230 VALU insts/wave/kt that R14's rolled loop
// recomputed (VALUBusy 32%).
__global__ __launch_bounds__(256, 4) void sim_kernel(const unsigned short* __restrict__ Z,
                                                     float* __restrict__ partial) {
  __shared__ __align__(16) unsigned short sA[BM * BK];   // 16 KiB
  __shared__ __align__(16) unsigned short sB[BN * BK];   // 16 KiB (total 32 KiB)

  // ---- block decode (lr: 64x64; ll: upper triangle of 64)
  int tm, tn; bool sym = false;
  {
    const int bid = blockIdx.x;
    if (bid < NLR_BLOCKS) {
      tm = bid >> 6; tn = 64 + (bid & 63);
    } else {
      const int b2 = bid - NLR_BLOCKS;            // 0..2079
      int i = (int)(64.5f - sqrtf(64.5f * 64.5f - 2.0f * (float)b2));
      if (i < 0) i = 0; if (i > 63) i = 63;
      while (i > 0 && (64 * i - i * (i - 1) / 2) > b2) --i;
      while (i < 63 && (64 * (i + 1) - (i + 1) * i / 2) <= b2) ++i;
      tm = i; tn = i + (b2 - (64 * i - i * (i - 1) / 2));
      sym = (tn != tm);
    }
  }

  const int t = threadIdx.x;
  const int l = t & 63;
  const int w = t >> 6;        // wave 0..3
  const int wm = w >> 1;       // 0..1  (64-row slab)
  const int wn = w & 1;        // 0..1  (64-col slab)
  const int lr = l & 15;
  const int lk = l >> 4;       // 0..3

  f32x4 acc[4][4];
#pragma unroll
  for (int a = 0; a < 4; ++a)
#pragma unroll
    for (int b = 0; b < 4; ++b)
#pragma unroll
      for (int r = 0; r < 4; ++r) acc[a][b][r] = 0.0f;

  // ---- hoisted addressing (all kt-invariant) ----
  // staging: per-lane global element offset + per-lane LDS dest
  const int srow = t >> 3;                       // 0..31
  const int scol = ((t & 7) ^ (srow & 7)) * 8;   // swizzled source element col
  const unsigned short* gA = Z + (size_t)tm * BM * DDIM + (size_t)srow * DDIM + scol;
  const unsigned short* gB = Z + (size_t)tn * BN * DDIM + (size_t)srow * DDIM + scol;
  unsigned short* lA = &sA[t * 8];
  unsigned short* lB = &sB[t * 8];
  // ds_read bases: row per matrix + 2 swizzled slot variants (ks = 0,1)
  const int swz0 = ((lk) ^ (lr & 7)) * 8;
  const int swz1 = ((4 + lk) ^ (lr & 7)) * 8;
  const unsigned short* rA0 = &sA[(wm * 64 + lr) * BK + swz0];
  const unsigned short* rA1 = &sA[(wm * 64 + lr) * BK + swz1];
  const unsigned short* rB0 = &sB[(wn * 64 + lr) * BK + swz0];
  const unsigned short* rB1 = &sB[(wn * 64 + lr) * BK + swz1];

  // j*32 rows = j*32*DDIM elements global; j*256 threads*8 = j*2048 elems LDS
#define STAGE_ALL(kt)                                                             \
  {                                                                               \
    _Pragma("unroll")                                                             \
    for (int j = 0; j < 4; ++j) {                                                 \
      __builtin_amdgcn_global_load_lds(                                           \
          (const __attribute__((address_space(1))) void*)(gA + (size_t)j * 32 * DDIM + (kt) * BK), \
          (__attribute__((address_space(3))) void*)(lA + j * 2048), 16, 0, 0);    \
    }                                                                             \
    _Pragma("unroll")                                                             \
    for (int j = 0; j < 4; ++j) {                                                 \
      __builtin_amdgcn_global_load_lds(                                           \
          (const __attribute__((address_space(1))) void*)(gB + (size_t)j * 32 * DDIM + (kt) * BK), \
          (__attribute__((address_space(3))) void*)(lB + j * 2048), 16, 0, 0);    \
    }                                                                             \
  }

  short8 af[4][2], bf[4][2];

  // fm row-block stride = 16 rows * BK = 1024 elems = 2048 B (offset:N imm)
#define DS_ALL                                                                     \
  _Pragma("unroll")                                                                \
  for (int fm = 0; fm < 4; ++fm) {                                                 \
    af[fm][0] = *(const short8*)(rA0 + fm * 16 * BK);                              \
    af[fm][1] = *(const short8*)(rA1 + fm * 16 * BK);                              \
    bf[fm][0] = *(const short8*)(rB0 + fm * 16 * BK);                              \
    bf[fm][1] = *(const short8*)(rB1 + fm * 16 * BK);                              \
  }

// ks OUTER: consecutive MFMAs hit distinct accumulators (dep distance 16).
#define MFMA32                                                                     \
  __builtin_amdgcn_s_setprio(1);                                                   \
  _Pragma("unroll")                                                                \
  for (int ks = 0; ks < 2; ++ks)                                                   \
    _Pragma("unroll")                                                              \
    for (int fm = 0; fm < 4; ++fm)                                                 \
      _Pragma("unroll")                                                            \
      for (int fn = 0; fn < 4; ++fn)                                               \
        acc[fm][fn] =                                                              \
            __builtin_amdgcn_mfma_f32_16x16x32_bf16(af[fm][ks], bf[fn][ks],        \
                                                    acc[fm][fn], 0, 0, 0);         \
  __builtin_amdgcn_s_setprio(0);

#define BARF  { __builtin_amdgcn_s_barrier(); asm volatile("" ::: "memory"); }
#define VM0   asm volatile("s_waitcnt vmcnt(0)" ::: "memory")

#pragma unroll
  for (int kt = 0; kt < KTILES; ++kt) {
    STAGE_ALL(kt);
    VM0;                       // exposed drain — covered by 3 co-resident blocks
    BARF;
    DS_ALL;
    MFMA32;
    BARF;                      // all reads of kt done -> licenses STAGE(kt+1)
  }

  // ---- Epilogue: e = exp(2*s); rowsums always, colsums when sym.
  // C/D layout (16x16x32): col = lane&15, row = (lane>>4)*4 + reg.
  // Overlay reductions onto sB (dead after final BAR; DMA drained at kt7 VM0).
  float* rsum = (float*)&sB[0];           // 128 floats
  float* csum = rsum + BM;                // 128 floats
  if (t < BM) { rsum[t] = 0.0f; csum[t] = 0.0f; }
  __syncthreads();
  float c0 = 0.0f, c1 = 0.0f, c2 = 0.0f, c3 = 0.0f;
#pragma unroll
  for (int fm = 0; fm < 4; ++fm) {
#pragma unroll
    for (int r = 0; r < 4; ++r) {
      float e0 = __expf(2.0f * acc[fm][0][r]);
      float e1 = __expf(2.0f * acc[fm][1][r]);
      float e2 = __expf(2.0f * acc[fm][2][r]);
      float e3 = __expf(2.0f * acc[fm][3][r]);
      float v = e0 + e1 + e2 + e3;
      v += __shfl_xor(v, 1);
      v += __shfl_xor(v, 2);
      v += __shfl_xor(v, 4);
      v += __shfl_xor(v, 8);
      if (lr == 0) atomicAdd(&rsum[wm * 64 + fm * 16 + lk * 4 + r], v);
      c0 += e0; c1 += e1; c2 += e2; c3 += e3;
    }
  }
  if (sym) {
    c0 += __shfl_xor(c0, 16); c0 += __shfl_xor(c0, 32);
    c1 += __shfl_xor(c1, 16); c1 += __shfl_xor(c1, 32);
    c2 += __shfl_xor(c2, 16); c2 += __shfl_xor(c2, 32);
    c3 += __shfl_xor(c3, 16); c3 += __shfl_xor(c3, 32);
    if (l < 16) {   // one lane per column per wave; 2 waves (wm) share a col
      atomicAdd(&csum[wn * 64 +  0 + lr], c0);
      atomicAdd(&csum[wn * 64 + 16 + lr], c1);
      atomicAdd(&csum[wn * 64 + 32 + lr], c2);
      atomicAdd(&csum[wn * 64 + 48 + lr], c3);
    }
  }
  __syncthreads();
  if (t < BM) partial[(size_t)tn * NROWS + tm * BM + t] = rsum[t];
  if (sym && t < BM) partial[(size_t)tm * NROWS + tn * BM + t] = csum[t];
}

// Kernel 3: reduce partials, final loss.
// loss[i] = log(rowsum - e^2) - 2*dlr[i]
__global__ __launch_bounds__(256) void fin_kernel(const float* __restrict__ partial,
                                                  const float* __restrict__ dlr,
                                                  float* __restrict__ out) {
  const int i = blockIdx.x * 256 + threadIdx.x;
  float s = 0.0f;
#pragma unroll 8
  for (int p = 0; p < NPANELS; ++p) s += partial[(size_t)p * NROWS + i];
  out[i] = logf(s - 7.38905609893065f) - 2.0f * dlr[i];
}

extern "C" void kernel_launch(void* const* d_in, const int* in_sizes, int n_in,
                              void* d_out, int out_size, void* d_ws, size_t ws_size,
                              hipStream_t stream) {
  const float* left = (const float*)d_in[0];
  const float* right = (const float*)d_in[1];
  float* out = (float*)d_out;

  unsigned short* Z = (unsigned short*)d_ws;                       // 16 MB
  char* p = (char*)d_ws + (size_t)ZROWS * DDIM * 2;
  float* dlr = (float*)p;                                          // 32 KB
  float* partial = (float*)(p + (size_t)NROWS * 4);                // 4 MB

  nrm_kernel<<<NROWS, 256, 0, stream>>>(left, right, Z, dlr);
  sim_kernel<<<NBLOCKS, 256, 0, stream>>>(Z, partial);
  fin_kernel<<<NROWS / 256, 256, 0, stream>>>(partial, dlr, out);
}

// Round 16
// 133.736 us; speedup vs baseline: 1.6746x; 1.6746x over previous
//
#include <hip/hip_runtime.h>

#define NROWS 8192
#define DDIM 512
#define ZROWS 16384
#define BM 128
#define BN 128
#define BK 64
#define KTILES (DDIM / BK)     // 8
#define NLR_BLOCKS 4096        // 64 x 64 (tm x lr-col-panel)
#define NSYM_BLOCKS 2080       // upper triangle incl diag of 64
#define NBLOCKS (NLR_BLOCKS + NSYM_BLOCKS)   // 6176
#define NPANELS 128            // 16384 / 128 col panels

typedef __attribute__((ext_vector_type(8))) short short8;
typedef __attribute__((ext_vector_type(4))) float f32x4;

__device__ __forceinline__ unsigned short f2bf(float f) {
  unsigned int u = __float_as_uint(f);
  u = (u + 0x7FFFu + ((u >> 16) & 1u)) >> 16;
  return (unsigned short)u;
}

// Kernel 1: per-row L2 normalize both inputs, write bf16 Z = [zl; zr],
// and compute the fp32 diagonal cosine sim dlr[i] = zl_i . zr_i.
__global__ __launch_bounds__(256) void nrm_kernel(const float* __restrict__ left,
                                                  const float* __restrict__ right,
                                                  unsigned short* __restrict__ Z,
                                                  float* __restrict__ dlr) {
  const int i = blockIdx.x;
  const int t = threadIdx.x;
  const float2 lv = ((const float2*)(left + (size_t)i * DDIM))[t];
  const float2 rv = ((const float2*)(right + (size_t)i * DDIM))[t];
  float ssl = lv.x * lv.x + lv.y * lv.y;
  float ssr = rv.x * rv.x + rv.y * rv.y;
  float slr = lv.x * rv.x + lv.y * rv.y;
#pragma unroll
  for (int m = 1; m < 64; m <<= 1) {
    ssl += __shfl_xor(ssl, m);
    ssr += __shfl_xor(ssr, m);
    slr += __shfl_xor(slr, m);
  }
  __shared__ float red[3][4];
  const int w = t >> 6;
  if ((t & 63) == 0) { red[0][w] = ssl; red[1][w] = ssr; red[2][w] = slr; }
  __syncthreads();
  ssl = red[0][0] + red[0][1] + red[0][2] + red[0][3];
  ssr = red[1][0] + red[1][1] + red[1][2] + red[1][3];
  slr = red[2][0] + red[2][1] + red[2][2] + red[2][3];
  const float invl = 1.0f / fmaxf(sqrtf(ssl), 1e-12f);
  const float invr = 1.0f / fmaxf(sqrtf(ssr), 1e-12f);
  if (t == 0) dlr[i] = slr * invl * invr;
  ushort2 zl2; zl2.x = f2bf(lv.x * invl); zl2.y = f2bf(lv.y * invl);
  ushort2 zr2; zr2.x = f2bf(rv.x * invr); zr2.y = f2bf(rv.y * invr);
  ((ushort2*)(Z + (size_t)i * DDIM))[t] = zl2;
  ((ushort2*)(Z + (size_t)(NROWS + i) * DDIM))[t] = zr2;
}

// Kernel 2: fused GEMM + exp-rowsum with ll-symmetry at 128^2 granularity.
// R14 base (4 blocks/CU via __launch_bounds__(256,4), single-buffered 32 KiB
// LDS, rolled loop, in-loop addressing — the proven no-spill config) with
// the per-kt schedule reordered to cover the DMA drain intra-block:
//   reads(af,bf01); MFMA(0); reads(bf23); lgkmcnt(0); BAR  <- LDS dead
//   STAGE(kt+1); MFMA(2) [covers DMA latency]; VM0; BAR    <- publish kt+1
// The explicit lgkmcnt(0) before the mid-barrier guarantees every wave's
// ds_reads are SERVICED (not just issued) before the DMA overwrites LDS.
// R15 lesson: no hoisted pointers, no full unroll (spilled at the 64-VGPR
// cap: WRITE_SIZE 4KB->392MB). Fragment liveness capped at 12 short8.
__global__ __launch_bounds__(256, 4) void sim_kernel(const unsigned short* __restrict__ Z,
                                                     float* __restrict__ partial) {
  __shared__ __align__(16) unsigned short sA[BM * BK];   // 16 KiB
  __shared__ __align__(16) unsigned short sB[BN * BK];   // 16 KiB (total 32 KiB)

  // ---- block decode (lr: 64x64; ll: upper triangle of 64)
  int tm, tn; bool sym = false;
  {
    const int bid = blockIdx.x;
    if (bid < NLR_BLOCKS) {
      tm = bid >> 6; tn = 64 + (bid & 63);
    } else {
      const int b2 = bid - NLR_BLOCKS;            // 0..2079
      int i = (int)(64.5f - sqrtf(64.5f * 64.5f - 2.0f * (float)b2));
      if (i < 0) i = 0; if (i > 63) i = 63;
      while (i > 0 && (64 * i - i * (i - 1) / 2) > b2) --i;
      while (i < 63 && (64 * (i + 1) - (i + 1) * i / 2) <= b2) ++i;
      tm = i; tn = i + (b2 - (64 * i - i * (i - 1) / 2));
      sym = (tn != tm);
    }
  }

  const int t = threadIdx.x;
  const int l = t & 63;
  const int w = t >> 6;        // wave 0..3
  const int wm = w >> 1;       // 0..1  (64-row slab)
  const int wn = w & 1;        // 0..1  (64-col slab)
  const int lr = l & 15;
  const int lk = l >> 4;       // 0..3

  f32x4 acc[4][4];
#pragma unroll
  for (int a = 0; a < 4; ++a)
#pragma unroll
    for (int b = 0; b < 4; ++b)
#pragma unroll
      for (int r = 0; r < 4; ++r) acc[a][b][r] = 0.0f;

  const unsigned short* Abase = Z + (size_t)tm * BM * DDIM;
  const unsigned short* Bbase = Z + (size_t)tn * BN * DDIM;

  // Staging: 256 threads x 16 B = 4 KB = 32 rows (128 B each) per gload.
  // LDS slot-linear; global source slot pre-swizzled by row&7; matching XOR
  // on ds_read (verified conflict-free).
  const int srow = t >> 3;                       // 0..31
  const int scol = ((t & 7) ^ (srow & 7)) * 8;   // swizzled source element col

#define STAGE_AJ(k0, j)                                                           \
  __builtin_amdgcn_global_load_lds(                                               \
      (const __attribute__((address_space(1))) void*)(Abase +                     \
          (size_t)((j) * 32 + srow) * DDIM + (k0) + scol),                        \
      (__attribute__((address_space(3))) void*)(&sA[((j) * 256 + t) * 8]),        \
      16, 0, 0);
#define STAGE_BJ(k0, j)                                                           \
  __builtin_amdgcn_global_load_lds(                                               \
      (const __attribute__((address_space(1))) void*)(Bbase +                     \
          (size_t)((j) * 32 + srow) * DDIM + (k0) + scol),                        \
      (__attribute__((address_space(3))) void*)(&sB[((j) * 256 + t) * 8]),        \
      16, 0, 0);
#define STAGE_ALL(k0) { STAGE_AJ(k0, 0) STAGE_AJ(k0, 1)                           \
                        STAGE_AJ(k0, 2) STAGE_AJ(k0, 3)                           \
                        STAGE_BJ(k0, 0) STAGE_BJ(k0, 1)                           \
                        STAGE_BJ(k0, 2) STAGE_BJ(k0, 3) }

  short8 af[4][2], bf[4][2];

#define DS_A(fmb)                                                                  \
  _Pragma("unroll")                                                                \
  for (int fm = 0; fm < 4; ++fm)                                                   \
    _Pragma("unroll")                                                              \
    for (int ks = 0; ks < 2; ++ks) {                                               \
      const int row = wm * 64 + fm * 16 + lr;                                      \
      af[fm][ks] = *(const short8*)&sA[row * BK + ((ks * 4 + lk) ^ (lr & 7)) * 8]; \
    }

#define DS_B2(fnb)                                                                 \
  _Pragma("unroll")                                                                \
  for (int fn = 0; fn < 2; ++fn)                                                   \
    _Pragma("unroll")                                                              \
    for (int ks = 0; ks < 2; ++ks) {                                               \
      const int row = wn * 64 + ((fnb) + fn) * 16 + lr;                            \
      bf[(fnb) + fn][ks] = *(const short8*)&sB[row * BK + ((ks * 4 + lk) ^ (lr & 7)) * 8]; \
    }

// ks OUTER: consecutive MFMAs hit distinct accumulators (dep distance 8).
#define MFMA16(fnb)                                                                \
  __builtin_amdgcn_s_setprio(1);                                                   \
  _Pragma("unroll")                                                                \
  for (int ks = 0; ks < 2; ++ks)                                                   \
    _Pragma("unroll")                                                              \
    for (int fm = 0; fm < 4; ++fm)                                                 \
      _Pragma("unroll")                                                            \
      for (int fn = 0; fn < 2; ++fn)                                               \
        acc[fm][(fnb) + fn] =                                                      \
            __builtin_amdgcn_mfma_f32_16x16x32_bf16(af[fm][ks], bf[(fnb) + fn][ks],\
                                                    acc[fm][(fnb) + fn],           \
                                                    0, 0, 0);                      \
  __builtin_amdgcn_s_setprio(0);

#define BARF  { __builtin_amdgcn_s_barrier(); asm volatile("" ::: "memory"); }
#define VM0   asm volatile("s_waitcnt vmcnt(0)" ::: "memory")
#define LGKM0 asm volatile("s_waitcnt lgkmcnt(0)" ::: "memory")

  // prologue: kt0 -> buffer; drain; publish.
  STAGE_ALL(0);
  VM0;
  BARF;

#pragma unroll 1
  for (int kt = 0; kt < KTILES; ++kt) {
    DS_A(0); DS_B2(0);
    MFMA16(0);                 // consumes bf01 while bf23 reads issue below
    DS_B2(2);
    LGKM0;                     // my reads SERVICED -> my LDS slice dead
    BARF;                      // all waves' reads serviced -> LDS dead
    if (kt + 1 < KTILES) STAGE_ALL((kt + 1) * BK);
    MFMA16(2);                 // covers DMA latency intra-block
    if (kt + 1 < KTILES) VM0;  // mostly drained already
    BARF;                      // publish kt+1 buffer
  }

  // ---- Epilogue: e = exp(2*s); rowsums always, colsums when sym.
  // C/D layout (16x16x32): col = lane&15, row = (lane>>4)*4 + reg.
  // Overlay reductions onto sB (dead after final BAR; no DMA outstanding).
  float* rsum = (float*)&sB[0];           // 128 floats
  float* csum = rsum + BM;                // 128 floats
  if (t < BM) { rsum[t] = 0.0f; csum[t] = 0.0f; }
  __syncthreads();
  float c0 = 0.0f, c1 = 0.0f, c2 = 0.0f, c3 = 0.0f;
#pragma unroll
  for (int fm = 0; fm < 4; ++fm) {
#pragma unroll
    for (int r = 0; r < 4; ++r) {
      float e0 = __expf(2.0f * acc[fm][0][r]);
      float e1 = __expf(2.0f * acc[fm][1][r]);
      float e2 = __expf(2.0f * acc[fm][2][r]);
      float e3 = __expf(2.0f * acc[fm][3][r]);
      float v = e0 + e1 + e2 + e3;
      v += __shfl_xor(v, 1);
      v += __shfl_xor(v, 2);
      v += __shfl_xor(v, 4);
      v += __shfl_xor(v, 8);
      if (lr == 0) atomicAdd(&rsum[wm * 64 + fm * 16 + lk * 4 + r], v);
      c0 += e0; c1 += e1; c2 += e2; c3 += e3;
    }
  }
  if (sym) {
    c0 += __shfl_xor(c0, 16); c0 += __shfl_xor(c0, 32);
    c1 += __shfl_xor(c1, 16); c1 += __shfl_xor(c1, 32);
    c2 += __shfl_xor(c2, 16); c2 += __shfl_xor(c2, 32);
    c3 += __shfl_xor(c3, 16); c3 += __shfl_xor(c3, 32);
    if (l < 16) {   // one lane per column per wave; 2 waves (wm) share a col
      atomicAdd(&csum[wn * 64 +  0 + lr], c0);
      atomicAdd(&csum[wn * 64 + 16 + lr], c1);
      atomicAdd(&csum[wn * 64 + 32 + lr], c2);
      atomicAdd(&csum[wn * 64 + 48 + lr], c3);
    }
  }
  __syncthreads();
  if (t < BM) partial[(size_t)tn * NROWS + tm * BM + t] = rsum[t];
  if (sym && t < BM) partial[(size_t)tm * NROWS + tn * BM + t] = csum[t];
}

// Kernel 3: reduce partials, final loss.
// loss[i] = log(rowsum - e^2) - 2*dlr[i]
__global__ __launch_bounds__(256) void fin_kernel(const float* __restrict__ partial,
                                                  const float* __restrict__ dlr,
                                                  float* __restrict__ out) {
  const int i = blockIdx.x * 256 + threadIdx.x;
  float s = 0.0f;
#pragma unroll 8
  for (int p = 0; p < NPANELS; ++p) s += partial[(size_t)p * NROWS + i];
  out[i] = logf(s - 7.38905609893065f) - 2.0f * dlr[i];
}

extern "C" void kernel_launch(void* const* d_in, const int* in_sizes, int n_in,
                              void* d_out, int out_size, void* d_ws, size_t ws_size,
                              hipStream_t stream) {
  const float* left = (const float*)d_in[0];
  const float* right = (const float*)d_in[1];
  float* out = (float*)d_out;

  unsigned short* Z = (unsigned short*)d_ws;                       // 16 MB
  char* p = (char*)d_ws + (size_t)ZROWS * DDIM * 2;
  float* dlr = (float*)p;                                          // 32 KB
  float* partial = (float*)(p + (size_t)NROWS * 4);                // 4 MB

  nrm_kernel<<<NROWS, 256, 0, stream>>>(left, right, Z, dlr);
  sim_kernel<<<NBLOCKS, 256, 0, stream>>>(Z, partial);
  fin_kernel<<<NROWS / 256, 256, 0, stream>>>(partial, dlr, out);
}

// Round 17
// 131.361 us; speedup vs baseline: 1.7049x; 1.0181x over previous
//
#include <hip/hip_runtime.h>

#define NROWS 8192
#define DDIM 512
#define ZROWS 16384
#define BM 128
#define BN 128
#define BK 64
#define KTILES (DDIM / BK)     // 8
#define NLR_BLOCKS 4096        // 64 x 64 (tm x lr-col-panel)
#define NSYM_BLOCKS 2080       // upper triangle incl diag of 64
#define NBLOCKS (NLR_BLOCKS + NSYM_BLOCKS)   // 6176
#define NPANELS 128            // 16384 / 128 col panels

typedef __attribute__((ext_vector_type(8))) short short8;
typedef __attribute__((ext_vector_type(4))) float f32x4;

__device__ __forceinline__ unsigned short f2bf(float f) {
  unsigned int u = __float_as_uint(f);
  u = (u + 0x7FFFu + ((u >> 16) & 1u)) >> 16;
  return (unsigned short)u;
}

// Kernel 1: per-row L2 normalize both inputs, write bf16 Z = [zl; zr], and
// compute fp32 dlr[i] = zl_i . zr_i. WAVE-PER-ROW (G13): float4 x2 per lane
// covers the 512-elem row in one wave; pure shfl_xor reduce (no LDS, no
// __syncthreads); ushort4 stores. 4 rows per 256-thread block.
__global__ __launch_bounds__(256) void nrm_kernel(const float* __restrict__ left,
                                                  const float* __restrict__ right,
                                                  unsigned short* __restrict__ Z,
                                                  float* __restrict__ dlr) {
  const int row = blockIdx.x * 4 + (threadIdx.x >> 6);
  const int l = threadIdx.x & 63;
  const float4* lrow = (const float4*)(left + (size_t)row * DDIM);
  const float4* rrow = (const float4*)(right + (size_t)row * DDIM);
  const float4 lv0 = lrow[l], lv1 = lrow[l + 64];
  const float4 rv0 = rrow[l], rv1 = rrow[l + 64];
  float ssl = lv0.x * lv0.x + lv0.y * lv0.y + lv0.z * lv0.z + lv0.w * lv0.w +
              lv1.x * lv1.x + lv1.y * lv1.y + lv1.z * lv1.z + lv1.w * lv1.w;
  float ssr = rv0.x * rv0.x + rv0.y * rv0.y + rv0.z * rv0.z + rv0.w * rv0.w +
              rv1.x * rv1.x + rv1.y * rv1.y + rv1.z * rv1.z + rv1.w * rv1.w;
  float slr = lv0.x * rv0.x + lv0.y * rv0.y + lv0.z * rv0.z + lv0.w * rv0.w +
              lv1.x * rv1.x + lv1.y * rv1.y + lv1.z * rv1.z + lv1.w * rv1.w;
#pragma unroll
  for (int m = 1; m < 64; m <<= 1) {
    ssl += __shfl_xor(ssl, m);
    ssr += __shfl_xor(ssr, m);
    slr += __shfl_xor(slr, m);
  }
  const float invl = 1.0f / fmaxf(sqrtf(ssl), 1e-12f);
  const float invr = 1.0f / fmaxf(sqrtf(ssr), 1e-12f);
  if (l == 0) dlr[row] = slr * invl * invr;
  ushort4 o;
  ushort4* zl = (ushort4*)(Z + (size_t)row * DDIM);
  ushort4* zr = (ushort4*)(Z + (size_t)(NROWS + row) * DDIM);
  o.x = f2bf(lv0.x * invl); o.y = f2bf(lv0.y * invl);
  o.z = f2bf(lv0.z * invl); o.w = f2bf(lv0.w * invl);
  zl[l] = o;
  o.x = f2bf(lv1.x * invl); o.y = f2bf(lv1.y * invl);
  o.z = f2bf(lv1.z * invl); o.w = f2bf(lv1.w * invl);
  zl[l + 64] = o;
  o.x = f2bf(rv0.x * invr); o.y = f2bf(rv0.y * invr);
  o.z = f2bf(rv0.z * invr); o.w = f2bf(rv0.w * invr);
  zr[l] = o;
  o.x = f2bf(rv1.x * invr); o.y = f2bf(rv1.y * invr);
  o.z = f2bf(rv1.z * invr); o.w = f2bf(rv1.w * invr);
  zr[l + 64] = o;
}

// Kernel 2: fused GEMM + exp-rowsum with ll-symmetry at 128^2 granularity.
// UNCHANGED from R16 (proven local optimum): 4 blocks/CU via
// __launch_bounds__(256,4), single-buffered 32 KiB LDS, rolled loop,
// in-loop addressing, per-kt schedule:
//   reads(af,bf01); MFMA16(0); reads(bf23); lgkmcnt(0); BAR  <- LDS dead
//   STAGE(kt+1); MFMA16(2) [covers DMA]; VM0; BAR            <- publish
// Deeper MFMA-after-stage splits need ~68 live VGPR (> 64 cap -> spill,
// R15 evidence); more blocks/CU need <=102 regs total (have 128). This is
// the operating point's ceiling.
__global__ __launch_bounds__(256, 4) void sim_kernel(const unsigned short* __restrict__ Z,
                                                     float* __restrict__ partial) {
  __shared__ __align__(16) unsigned short sA[BM * BK];   // 16 KiB
  __shared__ __align__(16) unsigned short sB[BN * BK];   // 16 KiB (total 32 KiB)

  // ---- block decode (lr: 64x64; ll: upper triangle of 64)
  int tm, tn; bool sym = false;
  {
    const int bid = blockIdx.x;
    if (bid < NLR_BLOCKS) {
      tm = bid >> 6; tn = 64 + (bid & 63);
    } else {
      const int b2 = bid - NLR_BLOCKS;            // 0..2079
      int i = (int)(64.5f - sqrtf(64.5f * 64.5f - 2.0f * (float)b2));
      if (i < 0) i = 0; if (i > 63) i = 63;
      while (i > 0 && (64 * i - i * (i - 1) / 2) > b2) --i;
      while (i < 63 && (64 * (i + 1) - (i + 1) * i / 2) <= b2) ++i;
      tm = i; tn = i + (b2 - (64 * i - i * (i - 1) / 2));
      sym = (tn != tm);
    }
  }

  const int t = threadIdx.x;
  const int l = t & 63;
  const int w = t >> 6;        // wave 0..3
  const int wm = w >> 1;       // 0..1  (64-row slab)
  const int wn = w & 1;        // 0..1  (64-col slab)
  const int lr = l & 15;
  const int lk = l >> 4;       // 0..3

  f32x4 acc[4][4];
#pragma unroll
  for (int a = 0; a < 4; ++a)
#pragma unroll
    for (int b = 0; b < 4; ++b)
#pragma unroll
      for (int r = 0; r < 4; ++r) acc[a][b][r] = 0.0f;

  const unsigned short* Abase = Z + (size_t)tm * BM * DDIM;
  const unsigned short* Bbase = Z + (size_t)tn * BN * DDIM;

  // Staging: 256 threads x 16 B = 4 KB = 32 rows (128 B each) per gload.
  // LDS slot-linear; global source slot pre-swizzled by row&7; matching XOR
  // on ds_read (verified conflict-free).
  const int srow = t >> 3;                       // 0..31
  const int scol = ((t & 7) ^ (srow & 7)) * 8;   // swizzled source element col

#define STAGE_AJ(k0, j)                                                           \
  __builtin_amdgcn_global_load_lds(                                               \
      (const __attribute__((address_space(1))) void*)(Abase +                     \
          (size_t)((j) * 32 + srow) * DDIM + (k0) + scol),                        \
      (__attribute__((address_space(3))) void*)(&sA[((j) * 256 + t) * 8]),        \
      16, 0, 0);
#define STAGE_BJ(k0, j)                                                           \
  __builtin_amdgcn_global_load_lds(                                               \
      (const __attribute__((address_space(1))) void*)(Bbase +                     \
          (size_t)((j) * 32 + srow) * DDIM + (k0) + scol),                        \
      (__attribute__((address_space(3))) void*)(&sB[((j) * 256 + t) * 8]),        \
      16, 0, 0);
#define STAGE_ALL(k0) { STAGE_AJ(k0, 0) STAGE_AJ(k0, 1)                           \
                        STAGE_AJ(k0, 2) STAGE_AJ(k0, 3)                           \
                        STAGE_BJ(k0, 0) STAGE_BJ(k0, 1)                           \
                        STAGE_BJ(k0, 2) STAGE_BJ(k0, 3) }

  short8 af[4][2], bf[4][2];

#define DS_A(fmb)                                                                  \
  _Pragma("unroll")                                                                \
  for (int fm = 0; fm < 4; ++fm)                                                   \
    _Pragma("unroll")                                                              \
    for (int ks = 0; ks < 2; ++ks) {                                               \
      const int row = wm * 64 + fm * 16 + lr;                                      \
      af[fm][ks] = *(const short8*)&sA[row * BK + ((ks * 4 + lk) ^ (lr & 7)) * 8]; \
    }

#define DS_B2(fnb)                                                                 \
  _Pragma("unroll")                                                                \
  for (int fn = 0; fn < 2; ++fn)                                                   \
    _Pragma("unroll")                                                              \
    for (int ks = 0; ks < 2; ++ks) {                                               \
      const int row = wn * 64 + ((fnb) + fn) * 16 + lr;                            \
      bf[(fnb) + fn][ks] = *(const short8*)&sB[row * BK + ((ks * 4 + lk) ^ (lr & 7)) * 8]; \
    }

// ks OUTER: consecutive MFMAs hit distinct accumulators (dep distance 8).
#define MFMA16(fnb)                                                                \
  __builtin_amdgcn_s_setprio(1);                                                   \
  _Pragma("unroll")                                                                \
  for (int ks = 0; ks < 2; ++ks)                                                   \
    _Pragma("unroll")                                                              \
    for (int fm = 0; fm < 4; ++fm)                                                 \
      _Pragma("unroll")                                                            \
      for (int fn = 0; fn < 2; ++fn)                                               \
        acc[fm][(fnb) + fn] =                                                      \
            __builtin_amdgcn_mfma_f32_16x16x32_bf16(af[fm][ks], bf[(fnb) + fn][ks],\
                                                    acc[fm][(fnb) + fn],           \
                                                    0, 0, 0);                      \
  __builtin_amdgcn_s_setprio(0);

#define BARF  { __builtin_amdgcn_s_barrier(); asm volatile("" ::: "memory"); }
#define VM0   asm volatile("s_waitcnt vmcnt(0)" ::: "memory")
#define LGKM0 asm volatile("s_waitcnt lgkmcnt(0)" ::: "memory")

  // prologue: kt0 -> buffer; drain; publish.
  STAGE_ALL(0);
  VM0;
  BARF;

#pragma unroll 1
  for (int kt = 0; kt < KTILES; ++kt) {
    DS_A(0); DS_B2(0);
    MFMA16(0);                 // consumes bf01 while bf23 reads issue below
    DS_B2(2);
    LGKM0;                     // my reads SERVICED -> my LDS slice dead
    BARF;                      // all waves' reads serviced -> LDS dead
    if (kt + 1 < KTILES) STAGE_ALL((kt + 1) * BK);
    MFMA16(2);                 // covers DMA latency intra-block
    if (kt + 1 < KTILES) VM0;  // mostly drained already
    BARF;                      // publish kt+1 buffer
  }

  // ---- Epilogue: e = exp(2*s); rowsums always, colsums when sym.
  // C/D layout (16x16x32): col = lane&15, row = (lane>>4)*4 + reg.
  // Overlay reductions onto sB (dead after final BAR; no DMA outstanding).
  float* rsum = (float*)&sB[0];           // 128 floats
  float* csum = rsum + BM;                // 128 floats
  if (t < BM) { rsum[t] = 0.0f; csum[t] = 0.0f; }
  __syncthreads();
  float c0 = 0.0f, c1 = 0.0f, c2 = 0.0f, c3 = 0.0f;
#pragma unroll
  for (int fm = 0; fm < 4; ++fm) {
#pragma unroll
    for (int r = 0; r < 4; ++r) {
      float e0 = __expf(2.0f * acc[fm][0][r]);
      float e1 = __expf(2.0f * acc[fm][1][r]);
      float e2 = __expf(2.0f * acc[fm][2][r]);
      float e3 = __expf(2.0f * acc[fm][3][r]);
      float v = e0 + e1 + e2 + e3;
      v += __shfl_xor(v, 1);
      v += __shfl_xor(v, 2);
      v += __shfl_xor(v, 4);
      v += __shfl_xor(v, 8);
      if (lr == 0) atomicAdd(&rsum[wm * 64 + fm * 16 + lk * 4 + r], v);
      c0 += e0; c1 += e1; c2 += e2; c3 += e3;
    }
  }
  if (sym) {
    c0 += __shfl_xor(c0, 16); c0 += __shfl_xor(c0, 32);
    c1 += __shfl_xor(c1, 16); c1 += __shfl_xor(c1, 32);
    c2 += __shfl_xor(c2, 16); c2 += __shfl_xor(c2, 32);
    c3 += __shfl_xor(c3, 16); c3 += __shfl_xor(c3, 32);
    if (l < 16) {   // one lane per column per wave; 2 waves (wm) share a col
      atomicAdd(&csum[wn * 64 +  0 + lr], c0);
      atomicAdd(&csum[wn * 64 + 16 + lr], c1);
      atomicAdd(&csum[wn * 64 + 32 + lr], c2);
      atomicAdd(&csum[wn * 64 + 48 + lr], c3);
    }
  }
  __syncthreads();
  if (t < BM) partial[(size_t)tn * NROWS + tm * BM + t] = rsum[t];
  if (sym && t < BM) partial[(size_t)tm * NROWS + tn * BM + t] = csum[t];
}

// Kernel 3: reduce partials, final loss.
// loss[i] = log(rowsum - e^2) - 2*dlr[i]
__global__ __launch_bounds__(256) void fin_kernel(const float* __restrict__ partial,
                                                  const float* __restrict__ dlr,
                                                  float* __restrict__ out) {
  const int i = blockIdx.x * 256 + threadIdx.x;
  float s = 0.0f;
#pragma unroll 8
  for (int p = 0; p < NPANELS; ++p) s += partial[(size_t)p * NROWS + i];
  out[i] = logf(s - 7.38905609893065f) - 2.0f * dlr[i];
}

extern "C" void kernel_launch(void* const* d_in, const int* in_sizes, int n_in,
                              void* d_out, int out_size, void* d_ws, size_t ws_size,
                              hipStream_t stream) {
  const float* left = (const float*)d_in[0];
  const float* right = (const float*)d_in[1];
  float* out = (float*)d_out;

  unsigned short* Z = (unsigned short*)d_ws;                       // 16 MB
  char* p = (char*)d_ws + (size_t)ZROWS * DDIM * 2;
  float* dlr = (float*)p;                                          // 32 KB
  float* partial = (float*)(p + (size_t)NROWS * 4);                // 4 MB

  nrm_kernel<<<NROWS / 4, 256, 0, stream>>>(left, right, Z, dlr);
  sim_kernel<<<NBLOCKS, 256, 0, stream>>>(Z, partial);
  fin_kernel<<<NROWS / 256, 256, 0, stream>>>(partial, dlr, out);
}